// Round 23
// baseline (19.931 us; speedup 1.0000x reference)
//
#include <hip/hip_runtime.h>
#include <math.h>

// Problem constants (from reference)
#define N_NODES 8192        // N_IN == N_OUT == 8192
#define C_OUT 32
constexpr float INV_RADIUS   = 1.0f / 0.1125f;   // RADIUS = 1.5*6*0.025/2
constexpr float EPS          = 1e-12f;
constexpr float FOUR_OVER_PI = 1.27323954473516f;

typedef __attribute__((ext_vector_type(8))) _Float16 half8;
typedef __attribute__((ext_vector_type(4))) float    floatx4;

// Fast hardware transcendentals (no IEEE-div sequence, no ocml calls).
__device__ __forceinline__ float frcp(float x)  { float r; asm("v_rcp_f32 %0, %1"  : "=v"(r) : "v"(x)); return r; }
__device__ __forceinline__ float frsq(float x)  { float r; asm("v_rsq_f32 %0, %1"  : "=v"(r) : "v"(x)); return r; }
__device__ __forceinline__ float fsqrt_(float x){ float r; asm("v_sqrt_f32 %0, %1" : "=v"(r) : "v"(x)); return r; }

__device__ __forceinline__ float sgnf(float v) {
    return (v > 0.f) ? 1.f : ((v < 0.f) ? -1.f : 0.f);
}

// pack two f32 -> one u32 of two f16
__device__ __forceinline__ unsigned pkh(float a, float b) {
    union { _Float16 h[2]; unsigned u; } x;
    x.h[0] = (_Float16)a; x.h[1] = (_Float16)b;
    return x.u;
}

// minimax odd polynomial for atan(q), |q| <= 1, max err ~1e-5
__device__ __forceinline__ float atan01(float q) {
    float t = q * q;
    float p = fmaf(t, -0.01172120f, 0.05265332f);
    p = fmaf(t, p, -0.11643287f);
    p = fmaf(t, p,  0.19354346f);
    p = fmaf(t, p, -0.33262347f);
    p = fmaf(t, p,  0.99997726f);
    return q * p;
}

// Workspace layout (d_ws):
//   pv   : 8192*8 floats                        = 262144 B @ 0
//   roff : 8193 ints                            =  32772 B @ 262144
//   W2h  : 32*200 f16  ([o][j] w/ pad to 200)   =  12800 B @ 294928
#define PV_OFF   0
#define ROFF_OFF 262144
#define W2H_OFF  294928

// Kernel 1: pv packing + W reorder + CSR row offsets via one coalesced
// boundary-detection pass, VECTORIZED 4 edges/thread (int4/float4).
// Capped key kc(e) = mask[e] ? dst[e] : N_NODES is non-decreasing; edge e
// covers n in (kc(e-1), kc(e)]. Ranges partition [0, N_NODES] -> each
// row_off entry written exactly once. (Padding guaranteed: E_PAD=600000 >
// real edge count, so row_off[N_NODES] is written by the first padded edge.)
__global__ __launch_bounds__(256) void prep_kernel(
    const float* __restrict__ pos0,
    const float* __restrict__ vel,
    const float* __restrict__ W,
    const int*   __restrict__ dst,
    const float* __restrict__ mask,
    int E,
    int*   __restrict__ row_off,
    float* __restrict__ pv,
    _Float16* __restrict__ W2h)
{
    int tid = blockIdx.x * blockDim.x + threadIdx.x;

    if (tid < 6400) {
        int o = tid / 200, j = tid - o * 200;
        _Float16 val = (_Float16)0.f;
        if (j < 192) {
            int nc = j >> 4, m = j & 15;
            int iz = m >> 2, iy = m & 3, ix = nc / 3, c = nc - ix * 3;
            int cell = (iz * 4 + iy) * 4 + ix;
            val = (_Float16)W[(cell * 3 + c) * 32 + o];
        }
        W2h[tid] = val;
    }
    if (tid < N_NODES) {
        float4 p = make_float4(pos0[3*tid+0], pos0[3*tid+1], pos0[3*tid+2], 0.f);
        float4 v = make_float4(vel [3*tid+0], vel [3*tid+1], vel [3*tid+2], 0.f);
        ((float4*)pv)[2*tid+0] = p;
        ((float4*)pv)[2*tid+1] = v;
    }

    int e0i = tid * 4;
    if (e0i >= E) return;
    int4   d4 = ((const int4*)dst)[tid];
    float4 m4 = ((const float4*)mask)[tid];
    int kcs[5];
    kcs[0] = (e0i == 0) ? -1
           : ((mask[e0i-1] != 0.f) ? min(dst[e0i-1], N_NODES) : N_NODES);
    kcs[1] = (m4.x != 0.f) ? min(d4.x, N_NODES) : N_NODES;
    kcs[2] = (m4.y != 0.f) ? min(d4.y, N_NODES) : N_NODES;
    kcs[3] = (m4.z != 0.f) ? min(d4.z, N_NODES) : N_NODES;
    kcs[4] = (m4.w != 0.f) ? min(d4.w, N_NODES) : N_NODES;
    #pragma unroll
    for (int i = 0; i < 4; ++i)
        for (int n = kcs[i] + 1; n <= kcs[i+1]; ++n)
            row_off[n] = e0i + i;
}

// Kernel 2: FUSED MFMA cconv + PER-WAVE output GEMV (no barriers at all).
// 8 nodes per block (8 waves, 512 threads), grid = 1024.
// LDS = records only, 36 KiB -> 4 blocks/CU = 32 waves/CU (100% cap).
// Stage 2 per wave: A[m][k] = G[k] broadcast (same fragment for every lane
// in a q-group -> every D row equals out[]); deposit G into the wave's own
// record buffer (wave-private, in-order -> no __syncthreads), 12 MFMAs,
// q==0 lanes store out = D[0][*] + b.
__global__ __launch_bounds__(512) void cconv_kernel(
    const float* __restrict__ pv,
    const float* __restrict__ pos1,
    const int*   __restrict__ src,
    const int*   __restrict__ row_off,
    const _Float16* __restrict__ W2h,
    const float* __restrict__ b,
    float* __restrict__ out)
{
    __shared__ float Glds[8][64 * 18];   // records: 8 waves x 64 x 72B = 36 KiB

    int t = threadIdx.x, wave = t >> 6, lane = t & 63;
    int q = lane >> 4, mr = lane & 15;
    int node = blockIdx.x * 8 + wave;

    floatx4 acc = {0.f, 0.f, 0.f, 0.f};

    float px = pos1[3*node+0], py = pos1[3*node+1], pz = pos1[3*node+2];
    int e0 = row_off[node], e1 = row_off[node+1];

    float* myrec = &Glds[wave][lane * 18];
    const _Float16* hp = (const _Float16*)&Glds[wave][0];

    for (int eb = e0; eb < e1; eb += 64) {
        int cnt = min(64, e1 - eb);          // wave-uniform
        bool valid = lane < cnt;
        int s = src[valid ? eb + lane : eb];
        float4 p = ((const float4*)pv)[2*s+0];
        float4 v = ((const float4*)pv)[2*s+1];

        // ---- geometry (lane-parallel) ----
        float rx = (p.x - px) * INV_RADIUS;
        float ry = (p.y - py) * INV_RADIUS;
        float rz = (p.z - pz) * INV_RADIUS;
        float r2 = rx*rx + ry*ry + rz*rz;
        float om  = 1.f - r2;
        float win = om * om * om;
        if (!valid || r2 >= 1.f) win = 0.f;

        float x = rx, y = ry, z = rz;
        float ax2y2 = x*x + y*y;
        float norm  = fsqrt_(r2 + EPS);
        bool  top   = 1.25f * z * z > ax2y2;
        float s_top  = fsqrt_(3.f * norm * frcp(norm + fabsf(z) + EPS));
        float s_side = norm * frsq(ax2y2 + EPS);
        float sel = top ? s_top : s_side;
        float cx = x * sel;
        float cy = y * sel;
        float cz = top ? sgnf(z) * norm : 1.5f * z;
        bool zero = r2 < 1e-12f;
        cx = zero ? 0.f : cx;  cy = zero ? 0.f : cy;  cz = zero ? 0.f : cz;

        float cx2 = cx*cx, cy2 = cy*cy;
        float nxy = fsqrt_(cx2 + cy2 + EPS);
        bool  c1  = cx2 >= cy2;
        float xs  = (fabsf(cx) > EPS) ? cx : 1.f;
        float ys  = (fabsf(cy) > EPS) ? cy : 1.f;
        float num = c1 ? cy : cx;
        float den = c1 ? xs : ys;
        float at  = atan01(num * frcp(den)) * FOUR_OVER_PI * nxy;
        float scx = sgnf(cx), scy = sgnf(cy);
        float ux = c1 ? scx * nxy : scy * at;
        float uy = c1 ? scx * at  : scy * nxy;
        bool zxy = (cx2 + cy2) < 1e-12f;
        ux = zxy ? 0.f : ux;  uy = zxy ? 0.f : uy;

        float gx = fminf(fmaxf((ux + 1.f) * 1.5f, 0.f), 3.f);
        float gy = fminf(fmaxf((uy + 1.f) * 1.5f, 0.f), 3.f);
        float gz = fminf(fmaxf((cz + 1.f) * 1.5f, 0.f), 3.f);

        float wvx = win * v.x, wvy = win * v.y, wvz = win * v.z;

        // separable hat factors (exactly reproduce trilinear corner weights)
        float hx0 = fmaxf(1.f - fabsf(gx - 0.f), 0.f);
        float hx1 = fmaxf(1.f - fabsf(gx - 1.f), 0.f);
        float hx2 = fmaxf(1.f - fabsf(gx - 2.f), 0.f);
        float hx3 = fmaxf(1.f - fabsf(gx - 3.f), 0.f);
        float hy0 = fmaxf(1.f - fabsf(gy - 0.f), 0.f);
        float hy1 = fmaxf(1.f - fabsf(gy - 1.f), 0.f);
        float hy2 = fmaxf(1.f - fabsf(gy - 2.f), 0.f);
        float hy3 = fmaxf(1.f - fabsf(gy - 3.f), 0.f);
        float hz0 = fmaxf(1.f - fabsf(gz - 0.f), 0.f);
        float hz1 = fmaxf(1.f - fabsf(gz - 1.f), 0.f);
        float hz2 = fmaxf(1.f - fabsf(gz - 2.f), 0.f);
        float hz3 = fmaxf(1.f - fabsf(gz - 3.f), 0.f);

        // A[m] = hz[m>>2]*hy[m&3] (16 halfs), B[n] = hx[n/3]*wv[n%3] (12+pad)
        unsigned A0 = pkh(hz0*hy0, hz0*hy1), A1 = pkh(hz0*hy2, hz0*hy3);
        unsigned A2 = pkh(hz1*hy0, hz1*hy1), A3 = pkh(hz1*hy2, hz1*hy3);
        unsigned A4 = pkh(hz2*hy0, hz2*hy1), A5 = pkh(hz2*hy2, hz2*hy3);
        unsigned A6 = pkh(hz3*hy0, hz3*hy1), A7 = pkh(hz3*hy2, hz3*hy3);
        unsigned B0 = pkh(hx0*wvx, hx0*wvy), B1 = pkh(hx0*wvz, hx1*wvx);
        unsigned B2 = pkh(hx1*wvy, hx1*wvz), B3 = pkh(hx2*wvx, hx2*wvy);
        unsigned B4 = pkh(hx2*wvz, hx3*wvx), B5 = pkh(hx3*wvy, hx3*wvz);

        float2* wp = (float2*)myrec;
        wp[0] = make_float2(__uint_as_float(A0), __uint_as_float(A1));
        wp[1] = make_float2(__uint_as_float(A2), __uint_as_float(A3));
        wp[2] = make_float2(__uint_as_float(A4), __uint_as_float(A5));
        wp[3] = make_float2(__uint_as_float(A6), __uint_as_float(A7));
        wp[4] = make_float2(__uint_as_float(B0), __uint_as_float(B1));
        wp[5] = make_float2(__uint_as_float(B2), __uint_as_float(B3));
        wp[6] = make_float2(__uint_as_float(B4), __uint_as_float(B5));
        wp[7] = make_float2(0.f, 0.f);       // zero pad (B cols 12..15)

        // ---- MFMA: K=32 records per call (compiler tracks LDS deps) ----
        int nkk = (cnt > 32) ? 2 : 1;
        for (int kk = 0; kk < nkk; ++kk) {
            union { _Float16 h[8]; half8 v8; } fa, fb;
            #pragma unroll
            for (int i = 0; i < 8; ++i) {
                int rec = kk * 32 + q * 8 + i;   // k-slot relabeling-invariant
                fa.h[i] = hp[rec * 36 + mr];          // A[m=mr] of record
                fb.h[i] = hp[rec * 36 + 16 + mr];     // B[n=mr] of record
            }
            acc = __builtin_amdgcn_mfma_f32_16x16x32_f16(fa.v8, fb.v8, acc, 0, 0, 0);
        }
    }

    // ---- Stage 2 (PER WAVE, no barrier): out[o] = sum_j G[j]*W2[j][o] + b ----
    // Deposit this wave's G tile as 192 f16 into its own record buffer:
    // G[j], j = mr*16 + 4q + reg  (guard mr<12: only j<192 real).
    _Float16* Gw = (_Float16*)&Glds[wave][0];
    if (mr < 12) {
        uint2 u = make_uint2(pkh(acc[0], acc[1]), pkh(acc[2], acc[3]));
        *(uint2*)&Gw[mr * 16 + 4 * q] = u;
    }
    // wave-private LDS, DS ops in-order per wave -> reads below see the writes

    floatx4 o0 = {0.f, 0.f, 0.f, 0.f};
    floatx4 o1 = {0.f, 0.f, 0.f, 0.f};
    #pragma unroll
    for (int kk = 0; kk < 6; ++kk) {
        // A broadcast: every lane in a q-group reads the same 8 G values
        // -> A[m][k] = G[k] for all m -> every D row equals out[].
        half8 af = *(const half8*)&Gw[kk * 32 + q * 8];
        half8 b0 = *(const half8*)&W2h[mr * 200 + kk * 32 + q * 8];        // global, L2
        half8 b1 = *(const half8*)&W2h[(16 + mr) * 200 + kk * 32 + q * 8]; // global, L2
        o0 = __builtin_amdgcn_mfma_f32_16x16x32_f16(af, b0, o0, 0, 0, 0);
        o1 = __builtin_amdgcn_mfma_f32_16x16x32_f16(af, b1, o1, 0, 0, 0);
    }
    // D[row][col]: rows identical; take row 0 (q==0, reg 0), col = mr.
    if (q == 0) {
        out[node * C_OUT + mr]      = o0[0] + b[mr];
        out[node * C_OUT + 16 + mr] = o1[0] + b[16 + mr];
    }
}

extern "C" void kernel_launch(void* const* d_in, const int* in_sizes, int n_in,
                              void* d_out, int out_size, void* d_ws, size_t ws_size,
                              hipStream_t stream)
{
    const float* vel  = (const float*)d_in[0];
    const float* pos0 = (const float*)d_in[1];
    const float* pos1 = (const float*)d_in[2];
    const float* W    = (const float*)d_in[3];
    const float* b    = (const float*)d_in[4];
    const int*   src  = (const int*)d_in[5];
    const int*   dst  = (const int*)d_in[6];
    const float* mask = (const float*)d_in[7];
    int E = in_sizes[5];

    char* ws = (char*)d_ws;
    float*    pv      = (float*)(ws + PV_OFF);
    int*      row_off = (int*)  (ws + ROFF_OFF);
    _Float16* W2h     = (_Float16*)(ws + W2H_OFF);

    // prep: E/4 boundary threads (150000 > 8192/6400 side-duty ranges)
    prep_kernel<<<(E / 4 + 255) / 256, 256, 0, stream>>>(pos0, vel, W, dst, mask, E, row_off, pv, W2h);
    cconv_kernel<<<N_NODES / 8, 512, 0, stream>>>(pv, pos1, src, row_off, W2h, b, (float*)d_out);
}

// Round 24
// 17.371 us; speedup vs baseline: 1.1474x; 1.1474x over previous
//
#include <hip/hip_runtime.h>
#include <math.h>

// Problem constants (from reference)
#define N_NODES 8192        // N_IN == N_OUT == 8192
#define C_OUT 32
constexpr float INV_RADIUS   = 1.0f / 0.1125f;   // RADIUS = 1.5*6*0.025/2
constexpr float EPS          = 1e-12f;
constexpr float FOUR_OVER_PI = 1.27323954473516f;

typedef __attribute__((ext_vector_type(8))) _Float16 half8;
typedef __attribute__((ext_vector_type(4))) float    floatx4;

// Fast hardware transcendentals (no IEEE-div sequence, no ocml calls).
__device__ __forceinline__ float frcp(float x)  { float r; asm("v_rcp_f32 %0, %1"  : "=v"(r) : "v"(x)); return r; }
__device__ __forceinline__ float frsq(float x)  { float r; asm("v_rsq_f32 %0, %1"  : "=v"(r) : "v"(x)); return r; }
__device__ __forceinline__ float fsqrt_(float x){ float r; asm("v_sqrt_f32 %0, %1" : "=v"(r) : "v"(x)); return r; }

__device__ __forceinline__ float sgnf(float v) {
    return (v > 0.f) ? 1.f : ((v < 0.f) ? -1.f : 0.f);
}

// pack two f32 -> one u32 of two f16
__device__ __forceinline__ unsigned pkh(float a, float b) {
    union { _Float16 h[2]; unsigned u; } x;
    x.h[0] = (_Float16)a; x.h[1] = (_Float16)b;
    return x.u;
}

// minimax odd polynomial for atan(q), |q| <= 1, max err ~1e-5
__device__ __forceinline__ float atan01(float q) {
    float t = q * q;
    float p = fmaf(t, -0.01172120f, 0.05265332f);
    p = fmaf(t, p, -0.11643287f);
    p = fmaf(t, p,  0.19354346f);
    p = fmaf(t, p, -0.33262347f);
    p = fmaf(t, p,  0.99997726f);
    return q * p;
}

// Workspace layout (d_ws):
//   pv   : 8192*8 floats                        = 262144 B @ 0
//   roff : 8193 ints                            =  32772 B @ 262144
//   W2h  : 32*200 f16  ([o][j] w/ pad to 200)   =  12800 B @ 294928
#define PV_OFF   0
#define ROFF_OFF 262144
#define W2H_OFF  294928

// Kernel 1: pv packing + W reorder + CSR row offsets via one coalesced
// boundary-detection pass, VECTORIZED 4 edges/thread (int4/float4).
// Capped key kc(e) = mask[e] ? dst[e] : N_NODES is non-decreasing; edge e
// covers n in (kc(e-1), kc(e)]. Ranges partition [0, N_NODES] -> each
// row_off entry written exactly once.
__global__ __launch_bounds__(256) void prep_kernel(
    const float* __restrict__ pos0,
    const float* __restrict__ vel,
    const float* __restrict__ W,
    const int*   __restrict__ dst,
    const float* __restrict__ mask,
    int E,
    int*   __restrict__ row_off,
    float* __restrict__ pv,
    _Float16* __restrict__ W2h)
{
    int tid = blockIdx.x * blockDim.x + threadIdx.x;

    if (tid < 6400) {
        int o = tid / 200, j = tid - o * 200;
        _Float16 val = (_Float16)0.f;
        if (j < 192) {
            int nc = j >> 4, m = j & 15;
            int iz = m >> 2, iy = m & 3, ix = nc / 3, c = nc - ix * 3;
            int cell = (iz * 4 + iy) * 4 + ix;
            val = (_Float16)W[(cell * 3 + c) * 32 + o];
        }
        W2h[tid] = val;
    }
    if (tid < N_NODES) {
        float4 p = make_float4(pos0[3*tid+0], pos0[3*tid+1], pos0[3*tid+2], 0.f);
        float4 v = make_float4(vel [3*tid+0], vel [3*tid+1], vel [3*tid+2], 0.f);
        ((float4*)pv)[2*tid+0] = p;
        ((float4*)pv)[2*tid+1] = v;
    }

    int e0i = tid * 4;
    if (e0i >= E) return;
    int4   d4 = ((const int4*)dst)[tid];
    float4 m4 = ((const float4*)mask)[tid];
    int kcs[5];
    kcs[0] = (e0i == 0) ? -1
           : ((mask[e0i-1] != 0.f) ? min(dst[e0i-1], N_NODES) : N_NODES);
    kcs[1] = (m4.x != 0.f) ? min(d4.x, N_NODES) : N_NODES;
    kcs[2] = (m4.y != 0.f) ? min(d4.y, N_NODES) : N_NODES;
    kcs[3] = (m4.z != 0.f) ? min(d4.z, N_NODES) : N_NODES;
    kcs[4] = (m4.w != 0.f) ? min(d4.w, N_NODES) : N_NODES;
    #pragma unroll
    for (int i = 0; i < 4; ++i)
        for (int n = kcs[i] + 1; n <= kcs[i+1]; ++n)
            row_off[n] = e0i + i;
}

// Kernel 2: FUSED MFMA cconv + per-node output GEMV (ROUND-22 structure:
// A_lds deposit + one barrier + wave-0-only stage 2 -- the per-wave stage 2
// of r23 duplicated W2h L2 reads 8x and regressed).
// 8 nodes per block (8 waves, 512 threads), grid = 1024.
__global__ __launch_bounds__(512) void cconv_kernel(
    const float* __restrict__ pv,
    const float* __restrict__ pos1,
    const int*   __restrict__ src,
    const int*   __restrict__ row_off,
    const _Float16* __restrict__ W2h,
    const float* __restrict__ b,
    float* __restrict__ out)
{
    __shared__ float    Glds[8][64 * 18];   // records: 8 waves x 64 x 72B = 36 KiB
    __shared__ _Float16 A_lds[16][200];     // 6.25 KiB (rows 8..15 unused garbage)

    int t = threadIdx.x, wave = t >> 6, lane = t & 63;
    int q = lane >> 4, mr = lane & 15;
    int node = blockIdx.x * 8 + wave;

    floatx4 acc = {0.f, 0.f, 0.f, 0.f};

    float px = pos1[3*node+0], py = pos1[3*node+1], pz = pos1[3*node+2];
    int e0 = row_off[node], e1 = row_off[node+1];

    float* myrec = &Glds[wave][lane * 18];
    const _Float16* hp = (const _Float16*)&Glds[wave][0];

    for (int eb = e0; eb < e1; eb += 64) {
        int cnt = min(64, e1 - eb);          // wave-uniform
        bool valid = lane < cnt;
        int s = src[valid ? eb + lane : eb];
        float4 p = ((const float4*)pv)[2*s+0];
        float4 v = ((const float4*)pv)[2*s+1];

        // ---- geometry (lane-parallel) ----
        float rx = (p.x - px) * INV_RADIUS;
        float ry = (p.y - py) * INV_RADIUS;
        float rz = (p.z - pz) * INV_RADIUS;
        float r2 = rx*rx + ry*ry + rz*rz;
        float om  = 1.f - r2;
        float win = om * om * om;
        if (!valid || r2 >= 1.f) win = 0.f;

        float x = rx, y = ry, z = rz;
        float ax2y2 = x*x + y*y;
        float norm  = fsqrt_(r2 + EPS);
        bool  top   = 1.25f * z * z > ax2y2;
        float s_top  = fsqrt_(3.f * norm * frcp(norm + fabsf(z) + EPS));
        float s_side = norm * frsq(ax2y2 + EPS);
        float sel = top ? s_top : s_side;
        float cx = x * sel;
        float cy = y * sel;
        float cz = top ? sgnf(z) * norm : 1.5f * z;
        bool zero = r2 < 1e-12f;
        cx = zero ? 0.f : cx;  cy = zero ? 0.f : cy;  cz = zero ? 0.f : cz;

        float cx2 = cx*cx, cy2 = cy*cy;
        float nxy = fsqrt_(cx2 + cy2 + EPS);
        bool  c1  = cx2 >= cy2;
        float xs  = (fabsf(cx) > EPS) ? cx : 1.f;
        float ys  = (fabsf(cy) > EPS) ? cy : 1.f;
        float num = c1 ? cy : cx;
        float den = c1 ? xs : ys;
        float at  = atan01(num * frcp(den)) * FOUR_OVER_PI * nxy;
        float scx = sgnf(cx), scy = sgnf(cy);
        float ux = c1 ? scx * nxy : scy * at;
        float uy = c1 ? scx * at  : scy * nxy;
        bool zxy = (cx2 + cy2) < 1e-12f;
        ux = zxy ? 0.f : ux;  uy = zxy ? 0.f : uy;

        float gx = fminf(fmaxf((ux + 1.f) * 1.5f, 0.f), 3.f);
        float gy = fminf(fmaxf((uy + 1.f) * 1.5f, 0.f), 3.f);
        float gz = fminf(fmaxf((cz + 1.f) * 1.5f, 0.f), 3.f);

        float wvx = win * v.x, wvy = win * v.y, wvz = win * v.z;

        // separable hat factors (exactly reproduce trilinear corner weights)
        float hx0 = fmaxf(1.f - fabsf(gx - 0.f), 0.f);
        float hx1 = fmaxf(1.f - fabsf(gx - 1.f), 0.f);
        float hx2 = fmaxf(1.f - fabsf(gx - 2.f), 0.f);
        float hx3 = fmaxf(1.f - fabsf(gx - 3.f), 0.f);
        float hy0 = fmaxf(1.f - fabsf(gy - 0.f), 0.f);
        float hy1 = fmaxf(1.f - fabsf(gy - 1.f), 0.f);
        float hy2 = fmaxf(1.f - fabsf(gy - 2.f), 0.f);
        float hy3 = fmaxf(1.f - fabsf(gy - 3.f), 0.f);
        float hz0 = fmaxf(1.f - fabsf(gz - 0.f), 0.f);
        float hz1 = fmaxf(1.f - fabsf(gz - 1.f), 0.f);
        float hz2 = fmaxf(1.f - fabsf(gz - 2.f), 0.f);
        float hz3 = fmaxf(1.f - fabsf(gz - 3.f), 0.f);

        // A[m] = hz[m>>2]*hy[m&3] (16 halfs), B[n] = hx[n/3]*wv[n%3] (12+pad)
        unsigned A0 = pkh(hz0*hy0, hz0*hy1), A1 = pkh(hz0*hy2, hz0*hy3);
        unsigned A2 = pkh(hz1*hy0, hz1*hy1), A3 = pkh(hz1*hy2, hz1*hy3);
        unsigned A4 = pkh(hz2*hy0, hz2*hy1), A5 = pkh(hz2*hy2, hz2*hy3);
        unsigned A6 = pkh(hz3*hy0, hz3*hy1), A7 = pkh(hz3*hy2, hz3*hy3);
        unsigned B0 = pkh(hx0*wvx, hx0*wvy), B1 = pkh(hx0*wvz, hx1*wvx);
        unsigned B2 = pkh(hx1*wvy, hx1*wvz), B3 = pkh(hx2*wvx, hx2*wvy);
        unsigned B4 = pkh(hx2*wvz, hx3*wvx), B5 = pkh(hx3*wvy, hx3*wvz);

        float2* wp = (float2*)myrec;
        wp[0] = make_float2(__uint_as_float(A0), __uint_as_float(A1));
        wp[1] = make_float2(__uint_as_float(A2), __uint_as_float(A3));
        wp[2] = make_float2(__uint_as_float(A4), __uint_as_float(A5));
        wp[3] = make_float2(__uint_as_float(A6), __uint_as_float(A7));
        wp[4] = make_float2(__uint_as_float(B0), __uint_as_float(B1));
        wp[5] = make_float2(__uint_as_float(B2), __uint_as_float(B3));
        wp[6] = make_float2(__uint_as_float(B4), __uint_as_float(B5));
        wp[7] = make_float2(0.f, 0.f);       // zero pad (B cols 12..15)

        // ---- MFMA: K=32 records per call (compiler tracks LDS deps) ----
        int nkk = (cnt > 32) ? 2 : 1;
        for (int kk = 0; kk < nkk; ++kk) {
            union { _Float16 h[8]; half8 v8; } fa, fb;
            #pragma unroll
            for (int i = 0; i < 8; ++i) {
                int rec = kk * 32 + q * 8 + i;   // k-slot relabeling-invariant
                fa.h[i] = hp[rec * 36 + mr];          // A[m=mr] of record
                fb.h[i] = hp[rec * 36 + 16 + mr];     // B[n=mr] of record
            }
            acc = __builtin_amdgcn_mfma_f32_16x16x32_f16(fa.v8, fb.v8, acc, 0, 0, 0);
        }
    }

    // ---- Stage 2: deposit tile as f16 A-row (j = n*16+m = mr*16+4q+reg) ----
    // GUARD mr<12: only B-cols 0..11 are real.
    if (mr < 12) {
        uint2 u = make_uint2(pkh(acc[0], acc[1]), pkh(acc[2], acc[3]));
        *(uint2*)&A_lds[wave][mr * 16 + 4 * q] = u;
    }
    __syncthreads();

    if (wave == 0) {
        floatx4 o0 = {0.f, 0.f, 0.f, 0.f};
        floatx4 o1 = {0.f, 0.f, 0.f, 0.f};
        #pragma unroll
        for (int kk = 0; kk < 6; ++kk) {
            half8 af = *(const half8*)&A_lds[mr][kk * 32 + q * 8];
            half8 b0 = *(const half8*)&W2h[mr * 200 + kk * 32 + q * 8];        // global, L2
            half8 b1 = *(const half8*)&W2h[(16 + mr) * 200 + kk * 32 + q * 8]; // global, L2
            o0 = __builtin_amdgcn_mfma_f32_16x16x32_f16(af, b0, o0, 0, 0, 0);
            o1 = __builtin_amdgcn_mfma_f32_16x16x32_f16(af, b1, o1, 0, 0, 0);
        }
        // D: row = 4q+reg, col = mr. Rows 0..7 (q<2) are the block's 8 nodes.
        if (q < 2) {
            int n0 = blockIdx.x * 8;
            float bv0 = b[mr], bv1 = b[16 + mr];
            #pragma unroll
            for (int r = 0; r < 4; ++r) {
                int nd = n0 + 4 * q + r;
                out[nd * C_OUT + mr]      = o0[r] + bv0;
                out[nd * C_OUT + 16 + mr] = o1[r] + bv1;
            }
        }
    }
}

extern "C" void kernel_launch(void* const* d_in, const int* in_sizes, int n_in,
                              void* d_out, int out_size, void* d_ws, size_t ws_size,
                              hipStream_t stream)
{
    const float* vel  = (const float*)d_in[0];
    const float* pos0 = (const float*)d_in[1];
    const float* pos1 = (const float*)d_in[2];
    const float* W    = (const float*)d_in[3];
    const float* b    = (const float*)d_in[4];
    const int*   src  = (const int*)d_in[5];
    const int*   dst  = (const int*)d_in[6];
    const float* mask = (const float*)d_in[7];
    int E = in_sizes[5];

    char* ws = (char*)d_ws;
    float*    pv      = (float*)(ws + PV_OFF);
    int*      row_off = (int*)  (ws + ROFF_OFF);
    _Float16* W2h     = (_Float16*)(ws + W2H_OFF);

    prep_kernel<<<(E / 4 + 255) / 256, 256, 0, stream>>>(pos0, vel, W, dst, mask, E, row_off, pv, W2h);
    cconv_kernel<<<N_NODES / 8, 512, 0, stream>>>(pv, pos1, src, row_off, W2h, b, (float*)d_out);
}